// Round 12
// baseline (201.815 us; speedup 1.0000x reference)
//
#include <hip/hip_runtime.h>
#include <stdint.h>

typedef float f32x4 __attribute__((ext_vector_type(4)));

#define NROWS 8192
#define DIM   1024
#define BK    128
#define NKT   (DIM / BK)   // 8
#define NB    (NROWS / 64) // 128 row-blocks
#define MARGIN 0.3f

// async global->LDS, 16B per lane; LDS dest = wave-uniform base + lane*16
#define GLOAD_LDS16(gp, lp)                                                    \
  __builtin_amdgcn_global_load_lds(                                            \
      (const __attribute__((address_space(1))) void*)(gp),                     \
      (__attribute__((address_space(3))) void*)(lp), 16, 0, 0)

// fp32 -> fp8 e4m3: 1 thread = 1 float4 -> 1 packed uint. Fully coalesced
// (R9 version had 64B-stride lanes -> 4x transactions). Zeroes loss[0].
__global__ __launch_bounds__(256) void cvt_f32_fp8(const float* __restrict__ in,
                                                   uint8_t* __restrict__ out,
                                                   float* __restrict__ loss) {
  if (blockIdx.x == 0 && threadIdx.x == 0) loss[0] = 0.0f;
  size_t i = ((size_t)blockIdx.x * 256 + threadIdx.x) * 4;
  float4 v = *(const float4*)(in + i);
  int w = 0;
  w = __builtin_amdgcn_cvt_pk_fp8_f32(v.x, v.y, w, false);
  w = __builtin_amdgcn_cvt_pk_fp8_f32(v.z, v.w, w, true);
  *(unsigned*)(out + i) = (unsigned)w;
}

// One block = one 64x64 tile of sim = A*A^T (upper triangle, bi<=bj).
// R12: max-TLP config. R9's 128-tile had ~3 blocks/CU; every phase's
// latency (L2 drain at the barrier) sat exposed (MfmaUtil 39%). 64-tile:
// acc=16 AGPR, ~60 regs total, LDS 16.5 KB -> 8 blocks/CU resident; 8
// independent phase streams interleave and hide each other's latency.
// Staging + XOR-swizzle + reader mapping identical to R9 (verified).
__global__ __launch_bounds__(256) void gram_loss(const uint8_t* __restrict__ A8,
                                                 const int* __restrict__ targets,
                                                 float* __restrict__ out) {
  __shared__ uint8_t As[64 * 128];   // 8 KB, swizzled [64][8 slots of 16B]
  __shared__ uint8_t Bs[64 * 128];   // 8 KB
  __shared__ int tRow[64];
  __shared__ int tCol[64];
  __shared__ float wsum[4];

  // linear block id -> (bi, bj), 0 <= bi <= bj < 128.
  // start(bi) = bi*(257-bi)/2 ; fp32 guess + exact while-loop fixup
  int t = blockIdx.x;
  int bi = (int)(0.5f * (257.0f - __builtin_sqrtf(257.0f * 257.0f - 8.0f * (float)t)));
  if (bi < 0) bi = 0;
  if (bi > NB - 1) bi = NB - 1;
  while (bi < NB - 1 && ((bi + 1) * (2 * NB + 1 - (bi + 1))) / 2 <= t) ++bi;
  while (bi > 0 && (bi * (2 * NB + 1 - bi)) / 2 > t) --bi;
  int bj = bi + (t - (bi * (2 * NB + 1 - bi)) / 2);

  const int iBase = bi * 64;
  const int jBase = bj * 64;

  const int tid  = threadIdx.x;
  const int wave = tid >> 6;
  const int lane = tid & 63;

  if (tid < 64) tRow[tid] = targets[iBase + tid];
  else if (tid < 128) tCol[tid - 64] = targets[jBase + tid - 64];

  // staging: tile halves. waves 0,1 stage A rows [sw*32, sw*32+32);
  // waves 2,3 stage B likewise. 2 loads per wave per phase (1 KB each:
  // 8 rows x 128B). lane -> row offset lane>>3, swizzled source col-group
  // (lane&7)^(lane>>3)  [row&7 == lane>>3: loads are 8-row aligned].
  const int sw   = wave & 1;                  // which 32-row half
  const int isB  = wave >> 1;                 // 0 = A-tile, 1 = B-tile
  const int lrow = lane >> 3;                 // 0..7 == row&7
  const int cg   = (lane & 7) ^ lrow;         // swizzled source col-group
  const uint8_t* gT = A8 + (size_t)((isB ? jBase : iBase) + sw * 32 + lrow) * DIM + cg * 16;
  uint8_t* lT = (isB ? Bs : As) + (sw * 32) * 128;

  const int m0 = (wave >> 1) * 32;
  const int n0 = (wave & 1) * 32;
  const int fr = lane & 15;    // row within 16-block
  const int h  = lane >> 4;    // 0..3: k-subgroup (8 bytes) within 32B k-step
  const int r7 = fr & 7;       // swizzle key (frag rows are 16-aligned)
  const int hHi = h >> 1;
  const int hLo = (h & 1) * 8;

  f32x4 acc[2][2] = {};

  for (int kt = 0; kt < NKT; ++kt) {
    __syncthreads();  // previous tile fully consumed
    const int kOff = kt * BK;
    GLOAD_LDS16(gT + kOff, lT);
    GLOAD_LDS16(gT + (size_t)8 * DIM + kOff, lT + 8 * 128);
    GLOAD_LDS16(gT + (size_t)16 * DIM + kOff, lT + 16 * 128);
    GLOAD_LDS16(gT + (size_t)24 * DIM + kOff, lT + 24 * 128);
    __syncthreads();  // vmcnt(0) drain + barrier: tile landed

    // 4 k-steps of 32; lane reads 8B of A/B per frag-row from swizzled slot
#pragma unroll
    for (int ks = 0; ks < 4; ++ks) {
      const int colOff = (((ks * 2 + hHi) ^ r7) * 16) + hLo;
      long af[2], bf[2];
#pragma unroll
      for (int mi = 0; mi < 2; ++mi)
        af[mi] = *(const long*)&As[(m0 + mi * 16 + fr) * 128 + colOff];
#pragma unroll
      for (int ni = 0; ni < 2; ++ni)
        bf[ni] = *(const long*)&Bs[(n0 + ni * 16 + fr) * 128 + colOff];
#pragma unroll
      for (int mi = 0; mi < 2; ++mi)
#pragma unroll
        for (int ni = 0; ni < 2; ++ni)
          acc[mi][ni] = __builtin_amdgcn_mfma_f32_16x16x32_fp8_fp8(
              af[mi], bf[ni], acc[mi][ni], 0, 0, 0);
    }
  }

  // epilogue: C/D layout col = lane&15, row = (lane>>4)*4 + reg (dtype-indep)
  const int col = lane & 15;
  const int rquad = (lane >> 4) * 4;
  float lsum = 0.0f;
#pragma unroll
  for (int ni = 0; ni < 2; ++ni) {
    const int tj = tCol[n0 + ni * 16 + col];
#pragma unroll
    for (int mi = 0; mi < 2; ++mi) {
#pragma unroll
      for (int r = 0; r < 4; ++r) {
        float s = acc[mi][ni][r];
        int ti = tRow[m0 + mi * 16 + rquad + r];
        lsum += (ti == tj) ? (s < 1.0f ? 1.0f - s : 0.0f)
                           : (s > MARGIN ? s : 0.0f);
      }
    }
  }
  if (bi != bj) lsum *= 2.0f;  // symmetric half counted twice

#pragma unroll
  for (int off = 32; off > 0; off >>= 1) lsum += __shfl_down(lsum, off, 64);
  if (lane == 0) wsum[wave] = lsum;
  __syncthreads();
  if (tid == 0)
    atomicAdd(out, (wsum[0] + wsum[1] + wsum[2] + wsum[3]) * (1.0f / (float)NROWS));
}

extern "C" void kernel_launch(void* const* d_in, const int* in_sizes, int n_in,
                              void* d_out, int out_size, void* d_ws, size_t ws_size,
                              hipStream_t stream) {
  const float* x = (const float*)d_in[0];
  const int* targets = (const int*)d_in[1];
  float* out = (float*)d_out;
  uint8_t* x8 = (uint8_t*)d_ws;  // 8192*1024 = 8 MiB scratch

  cvt_f32_fp8<<<8192, 256, 0, stream>>>(x, x8, out);      // 8388608 = 8192*256*4
  gram_loss<<<NB * (NB + 1) / 2, 256, 0, stream>>>(x8, targets, out);  // 8256
}

// Round 13
// 150.996 us; speedup vs baseline: 1.3366x; 1.3366x over previous
//
#include <hip/hip_runtime.h>
#include <stdint.h>

typedef float f32x4 __attribute__((ext_vector_type(4)));

#define NROWS 8192
#define DIM   1024
#define BK    256
#define NKT   (DIM / BK)   // 4
#define MARGIN 0.3f

// async global->LDS, 16B per lane; LDS dest = wave-uniform base + lane*16
#define GLOAD_LDS16(gp, lp)                                                    \
  __builtin_amdgcn_global_load_lds(                                            \
      (const __attribute__((address_space(1))) void*)(gp),                     \
      (__attribute__((address_space(3))) void*)(lp), 16, 0, 0)

// fp32 -> fp8 e4m3: 1 thread = 1 float4 -> 1 packed uint, fully coalesced.
// Zeroes loss[0].
__global__ __launch_bounds__(256) void cvt_f32_fp8(const float* __restrict__ in,
                                                   uint8_t* __restrict__ out,
                                                   float* __restrict__ loss) {
  if (blockIdx.x == 0 && threadIdx.x == 0) loss[0] = 0.0f;
  size_t i = ((size_t)blockIdx.x * 256 + threadIdx.x) * 4;
  float4 v = *(const float4*)(in + i);
  int w = 0;
  w = __builtin_amdgcn_cvt_pk_fp8_f32(v.x, v.y, w, false);
  w = __builtin_amdgcn_cvt_pk_fp8_f32(v.z, v.w, w, true);
  *(unsigned*)(out + i) = (unsigned)w;
}

// One block = one 128x128 tile of sim = A*A^T (upper triangle, bi<=bj).
// fp8 e4m3, mfma_f32_16x16x32_fp8_fp8. R13: BK=256 -> 4 drain phases (half
// of R9) with 2x bytes in flight per drain. Rationale (R12 post-mortem):
// the per-phase stall is a shared fetch-path queue (beyond-L2); R1 showed
// 1.38 TB/s achievable, R9 ran it at 0.89 -> batch bigger, drain less often.
// 128-tile keeps FETCH at the ~62 MB floor (R12's 64-tile doubled it).
//
// LDS [128 rows][256 B] = row stride 2x bank wrap -> XOR swizzle over 16
// slots: slot s ^ (row&15) holds global col-group s (applied on the GLOBAL
// source per lane; global_load_lds pins LDS slot = lane*16B). Reader:
// colOff = ((ks*2+hHi) ^ fr)*16 + hLo -> 8 bank-groups x 2 lanes = free.
__global__ __launch_bounds__(256) void gram_loss(const uint8_t* __restrict__ A8,
                                                 const int* __restrict__ targets,
                                                 float* __restrict__ out) {
  __shared__ uint8_t As[128 * 256];   // 32 KB, swizzled [128][16 slots of 16B]
  __shared__ uint8_t Bs[128 * 256];   // 32 KB
  __shared__ int tRow[128];
  __shared__ int tCol[128];
  __shared__ float wsum[4];

  // linear block id -> (bi, bj) with 0 <= bi <= bj < 64  (fp32 guess + exact fixup)
  int t = blockIdx.x;
  int bi = (int)(0.5f * (129.0f - __builtin_sqrtf(129.0f * 129.0f - 8.0f * (float)t)));
  if (bi < 0) bi = 0;
  if (bi > 63) bi = 63;
  while (bi < 63 && ((bi + 1) * (129 - (bi + 1))) / 2 <= t) ++bi;
  while (bi > 0 && (bi * (129 - bi)) / 2 > t) --bi;
  int bj = bi + (t - (bi * (129 - bi)) / 2);

  const int iBase = bi * 128;
  const int jBase = bj * 128;

  const int tid  = threadIdx.x;
  const int wave = tid >> 6;
  const int lane = tid & 63;

  if (tid < 128) tRow[tid] = targets[iBase + tid];
  else           tCol[tid - 128] = targets[jBase + tid - 128];

  // staging: waves 0,1 stage A rows [(wave&1)*64, +64); waves 2,3 stage B.
  // 16 loads/wave/phase; one load = 64 lanes x 16B = 4 rows x 256B.
  // lane -> row-in-load lane>>4 (0..3), col-slot lane&15; SWIZZLED global
  // col-group = (lane&15) ^ (row&15).
  const int half = wave & 1;                  // which 64-row half
  const int isB  = wave >> 1;                 // 0 = A-tile, 1 = B-tile
  const int lrow = lane >> 4;                 // 0..3: row within 4-row load
  const int cs   = lane & 15;                 // LDS col-slot (pinned)
  const uint8_t* gBase = A8 + (size_t)((isB ? jBase : iBase) + half * 64) * DIM;
  uint8_t* lT = (isB ? Bs : As) + half * 64 * 256;

  const int m0 = (wave >> 1) * 64;
  const int n0 = (wave & 1) * 64;
  const int fr = lane & 15;    // row within 16-block (== row&15 of frag rows)
  const int h  = lane >> 4;    // 0..3: k-subgroup (8 bytes) within 32B k-step
  const int hHi = h >> 1;
  const int hLo = (h & 1) * 8;

  f32x4 acc[4][4] = {};

  for (int kt = 0; kt < NKT; ++kt) {
    __syncthreads();  // previous tile fully consumed
    const int kOff = kt * BK;
#pragma unroll
    for (int l = 0; l < 16; ++l) {
      const int r = l * 4 + lrow;                      // row within 64-half
      const int scg = cs ^ (r & 15);                   // swizzled source col-group
      GLOAD_LDS16(gBase + (size_t)r * DIM + kOff + scg * 16, lT + l * 1024);
    }
    __syncthreads();  // vmcnt(0) drain + barrier: tile landed

    // 8 k-steps of 32; lane reads 8B of A/B per frag-row from swizzled slot
#pragma unroll
    for (int ks = 0; ks < 8; ++ks) {
      const int colOff = (((ks * 2 + hHi) ^ fr) * 16) + hLo;
      long af[4], bf[4];
#pragma unroll
      for (int mi = 0; mi < 4; ++mi)
        af[mi] = *(const long*)&As[(m0 + mi * 16 + fr) * 256 + colOff];
#pragma unroll
      for (int ni = 0; ni < 4; ++ni)
        bf[ni] = *(const long*)&Bs[(n0 + ni * 16 + fr) * 256 + colOff];
#pragma unroll
      for (int mi = 0; mi < 4; ++mi)
#pragma unroll
        for (int ni = 0; ni < 4; ++ni)
          acc[mi][ni] = __builtin_amdgcn_mfma_f32_16x16x32_fp8_fp8(
              af[mi], bf[ni], acc[mi][ni], 0, 0, 0);
    }
  }

  // epilogue: C/D layout col = lane&15, row = (lane>>4)*4 + reg (dtype-indep)
  const int col = lane & 15;
  const int rquad = (lane >> 4) * 4;
  float lsum = 0.0f;
#pragma unroll
  for (int ni = 0; ni < 4; ++ni) {
    const int tj = tCol[n0 + ni * 16 + col];
#pragma unroll
    for (int mi = 0; mi < 4; ++mi) {
#pragma unroll
      for (int r = 0; r < 4; ++r) {
        float s = acc[mi][ni][r];
        int ti = tRow[m0 + mi * 16 + rquad + r];
        lsum += (ti == tj) ? (s < 1.0f ? 1.0f - s : 0.0f)
                           : (s > MARGIN ? s : 0.0f);
      }
    }
  }
  if (bi != bj) lsum *= 2.0f;  // symmetric half counted twice

#pragma unroll
  for (int off = 32; off > 0; off >>= 1) lsum += __shfl_down(lsum, off, 64);
  if (lane == 0) wsum[wave] = lsum;
  __syncthreads();
  if (tid == 0)
    atomicAdd(out, (wsum[0] + wsum[1] + wsum[2] + wsum[3]) * (1.0f / (float)NROWS));
}

extern "C" void kernel_launch(void* const* d_in, const int* in_sizes, int n_in,
                              void* d_out, int out_size, void* d_ws, size_t ws_size,
                              hipStream_t stream) {
  const float* x = (const float*)d_in[0];
  const int* targets = (const int*)d_in[1];
  float* out = (float*)d_out;
  uint8_t* x8 = (uint8_t*)d_ws;  // 8192*1024 = 8 MiB scratch

  cvt_f32_fp8<<<8192, 256, 0, stream>>>(x, x8, out);      // 8388608 = 8192*256*4
  gram_loss<<<2080, 256, 0, stream>>>(x8, targets, out);  // 64*65/2 upper-tri blocks
}